// Round 11
// baseline (1052.732 us; speedup 1.0000x reference)
//
#include <hip/hip_runtime.h>
#include <cstdio>
#include <cstdint>

typedef _Float16 f16;
typedef _Float16 f16x8 __attribute__((ext_vector_type(8)));
typedef float f32x4 __attribute__((ext_vector_type(4)));

#define D_MODEL 2048
#define FFN     4096
#define FFN2    8192
#define NEXP    8
#define NTOK    4096
#define NENT    (NTOK*2)
#define BM      256
#define BN      256
#define BK      64
#define KSPLIT  4
#define KCHUNK  (FFN / KSPLIT)   // 1024
#define MAX_ROWS  10240  // sum over experts of ceil(cnt/256)*256 <= 10232
#define MAX_TILES 40     // sum ceil(cnt/256) <= 39

__device__ __forceinline__ void gload_lds16(const void* g, void* l) {
  __builtin_amdgcn_global_load_lds(
      (const __attribute__((address_space(1))) void*)g,
      (__attribute__((address_space(3))) void*)l, 16, 0, 0);
}

template<int N> __device__ __forceinline__ void waitvm() {
  if constexpr (N == 0) asm volatile("s_waitcnt vmcnt(0)" ::: "memory");
  else if constexpr (N == 8) asm volatile("s_waitcnt vmcnt(8)" ::: "memory");
  // N < 0: no wait
}

// ---- staging: chunk = 16KB (2 gload_lds/thread), linear LDS dest, XOR
// swizzle folded into the per-lane GLOBAL source column (rule #21).
template<int LD>
__device__ __forceinline__ void stageA(const f16* aT, int k0, f16* AS, int mh, int tid) {
#pragma unroll
  for (int s = 0; s < 2; s++) {
    int o = s*8192 + tid*16;
    int rl = o >> 7;                                  // storage-local row 0..127
    int ce = ((o & 127) ^ ((rl & 7) << 4)) >> 1;      // pre-swizzled source col (f16)
    int arow = s*128 + mh*64 + (rl & 63);             // actual A row in tile
    gload_lds16(aT + (size_t)arow * LD + k0 + ce,
                (char*)AS + mh*16384 + s*8192 + (tid & ~63)*16);
  }
}

template<int LD>
__device__ __forceinline__ void stageB(const f16* bT, int k0, f16* BS, int nh, int tid) {
#pragma unroll
  for (int s = 0; s < 2; s++) {
    int o = s*8192 + tid*16;
    int rl = o >> 7;
    int ce = ((o & 127) ^ ((rl & 7) << 4)) >> 1;
    int crow = (rl >> 5)*64 + nh*32 + (rl & 31);      // actual B row (tile col)
    gload_lds16(bT + (size_t)crow * LD + k0 + ce,
                (char*)BS + nh*16384 + s*8192 + (tid & ~63)*16);
  }
}

__device__ __forceinline__ f16x8 fragLd(const f16* S, int row, int lane, int ks) {
  int kb = ks*64 + (lane >> 4)*16;
  int off = (row*128 + kb) ^ ((row & 7) << 4);
  return *(const f16x8*)((const char*)S + off);
}

__device__ __forceinline__ void quad(
    f32x4 (&acc)[8][4], int mo, int no,
    f16x8 (&aFh)[4][2], f16x8 (&bFh)[2][2]) {
#pragma unroll
  for (int mf = 0; mf < 4; mf++)
#pragma unroll
    for (int nf = 0; nf < 2; nf++)
#pragma unroll
      for (int ks = 0; ks < 2; ks++)
        acc[mo+mf][no+nf] = __builtin_amdgcn_mfma_f32_16x16x32_f16(
            aFh[mf][ks], bFh[nf][ks], acc[mo+mf][no+nf], 0, 0, 0);
}

// ---- R11 "reads-early / stages-late" K-tile (4 phases, 8 barriers kept):
//  ph0: read aF0 (A-h0, 8) + bF0 (4)      | MFMA Q00
//  ph1: read bF1 (4) + aF1 (A-h1, 8 regs) | MFMA Q01   <- A,B bufs DEAD after
//  ph2: stage B(t+2) -> CURRENT BSc       | MFMA Q10 (aF1 from regs)
//  ph3: stage A(t+2) -> CURRENT ASc       | MFMA Q11; vmcnt(8); barrier
// Ledger (induction): entering t, 8 in flight = tile t+1's chunks, issued
// during t-1 (~2 tiles ~ 12k cyc old >> HBM latency). During t issue 8
// (t+2 -> buf[t&1]; parity (t+2)&1 == t&1). End vmcnt(8) retires the 8
// oldest = everything t+1 reads. Writes into ASc/BSc happen at ph2/ph3,
// strictly after the ph1-end barrier ==> all reads of those bufs retired.
// Tails: t=NT-2 {no stage, vmcnt(0)}, t=NT-1 {no stage, no wait}.
template<int LD, int VEND, bool STG>
__device__ __forceinline__ void tile4v2(
    const f16* aT, const f16* bT, int k2,
    f16* ASc, f16* BSc,
    f32x4 (&acc)[8][4],
    int tid, int lane, int wrM, int wcN) {
  f16x8 aF0[4][2], aF1[4][2], bF[2][2][2];
  int i15 = lane & 15;
  // ---- phase 0: read A-h0 + B-h0; MFMA Q00
#pragma unroll
  for (int mf = 0; mf < 4; mf++)
#pragma unroll
    for (int ks = 0; ks < 2; ks++)
      aF0[mf][ks] = fragLd(ASc, wrM*64 + mf*16 + i15, lane, ks);
#pragma unroll
  for (int nf = 0; nf < 2; nf++)
#pragma unroll
    for (int ks = 0; ks < 2; ks++)
      bF[0][nf][ks] = fragLd(BSc, wcN*32 + nf*16 + i15, lane, ks);
  __builtin_amdgcn_s_barrier();
  __builtin_amdgcn_s_setprio(1);
  quad(acc, 0, 0, aF0, bF[0]);
  __builtin_amdgcn_s_setprio(0);
  __builtin_amdgcn_s_barrier();
  // ---- phase 1: read B-h1 first (needed this phase), then A-h1 into aF1
#pragma unroll
  for (int nf = 0; nf < 2; nf++)
#pragma unroll
    for (int ks = 0; ks < 2; ks++)
      bF[1][nf][ks] = fragLd(BSc, 128 + wcN*32 + nf*16 + i15, lane, ks);
#pragma unroll
  for (int mf = 0; mf < 4; mf++)
#pragma unroll
    for (int ks = 0; ks < 2; ks++)
      aF1[mf][ks] = fragLd(ASc, 128 + wrM*64 + mf*16 + i15, lane, ks);
  __builtin_amdgcn_s_barrier();
  __builtin_amdgcn_s_setprio(1);
  quad(acc, 0, 2, aF0, bF[1]);
  __builtin_amdgcn_s_setprio(0);
  __builtin_amdgcn_s_barrier();
  // ---- phase 2: stage B(t+2) into current BSc (dead); MFMA Q10
  if constexpr (STG) {
    stageB<LD>(bT, k2, BSc, 0, tid);
    stageB<LD>(bT, k2, BSc, 1, tid);
  }
  __builtin_amdgcn_s_barrier();
  __builtin_amdgcn_s_setprio(1);
  quad(acc, 4, 0, aF1, bF[0]);
  __builtin_amdgcn_s_setprio(0);
  __builtin_amdgcn_s_barrier();
  // ---- phase 3: stage A(t+2) into current ASc (dead); MFMA Q11
  if constexpr (STG) {
    stageA<LD>(aT, k2, ASc, 0, tid);
    stageA<LD>(aT, k2, ASc, 1, tid);
  }
  __builtin_amdgcn_s_barrier();
  __builtin_amdgcn_s_setprio(1);
  quad(acc, 4, 2, aF1, bF[1]);
  __builtin_amdgcn_s_setprio(0);
  waitvm<VEND>();
  __builtin_amdgcn_s_barrier();
}

// ---------------- utility kernels ----------------

__global__ void zero_counts_kernel(int* counts) {
  if (threadIdx.x < NEXP) counts[threadIdx.x] = 0;
}

// ---------------- router ----------------
__global__ __launch_bounds__(64) void router_kernel(
    const float* __restrict__ x, const float* __restrict__ rw,
    int* counts, int* te, float* tw, int* trank) {
  int t = blockIdx.x;
  int lane = threadIdx.x;
  float acc[8] = {0.f,0.f,0.f,0.f,0.f,0.f,0.f,0.f};
  const float* xr = x + (size_t)t * D_MODEL;
  for (int d = lane; d < D_MODEL; d += 64) {
    float xv = xr[d];
    const float4* r4 = (const float4*)(rw + (size_t)d * NEXP);
    float4 a = r4[0], b = r4[1];
    acc[0] += xv*a.x; acc[1] += xv*a.y; acc[2] += xv*a.z; acc[3] += xv*a.w;
    acc[4] += xv*b.x; acc[5] += xv*b.y; acc[6] += xv*b.z; acc[7] += xv*b.w;
  }
#pragma unroll
  for (int off = 32; off > 0; off >>= 1) {
#pragma unroll
    for (int e = 0; e < 8; e++) acc[e] += __shfl_down(acc[e], off);
  }
  if (lane == 0) {
    int e0 = 0;
#pragma unroll
    for (int e = 1; e < 8; e++) if (acc[e] > acc[e0]) e0 = e;
    int e1 = (e0 == 0) ? 1 : 0;
#pragma unroll
    for (int e = 0; e < 8; e++) if (e != e0 && acc[e] > acc[e1]) e1 = e;
    float c0 = 1.0f / (1.0f + expf(acc[e1] - acc[e0]));   // == softmax-top2 L1-renorm
    float c1 = 1.0f - c0;
    int r0 = atomicAdd(&counts[e0], 1);
    int r1 = atomicAdd(&counts[e1], 1);
    te[t*2] = e0; te[t*2+1] = e1;
    tw[t*2] = c0; tw[t*2+1] = c1;
    trank[t*2] = r0; trank[t*2+1] = r1;
  }
}

// ---------------- scan + tile schedule ----------------
__global__ void sched_kernel(const int* counts, int* offsets, int4* sched, int* nT) {
  if (threadIdx.x != 0 || blockIdx.x != 0) return;
  int off = 0, n = 0;
  for (int e = 0; e < NEXP; e++) {
    offsets[e] = off;
    int cnt = counts[e];
    int nt = (cnt + BM - 1) / BM;
    for (int i = 0; i < nt; i++) {
      sched[n] = make_int4(e, off + i*BM, min(BM, cnt - i*BM), 0);
      n++;
    }
    off += nt * BM;
  }
  offsets[NEXP] = off;
  *nT = n;
}

// ---------------- gather x rows -> f16 xg[slot] ----------------
__global__ __launch_bounds__(256) void gather_kernel(
    const float* __restrict__ x, const int* __restrict__ te,
    const float* __restrict__ tw, const int* __restrict__ trank,
    const int* __restrict__ offsets, f16* __restrict__ xg,
    int* __restrict__ token_of, float* __restrict__ coefs) {
  int i = blockIdx.x;
  int t = i >> 1;
  int e = te[i];
  int slot = offsets[e] + trank[i];
  if (threadIdx.x == 0) { token_of[slot] = t; coefs[slot] = tw[i]; }
  const float4* src = (const float4*)(x + (size_t)t * D_MODEL);
  f16x8* dst = (f16x8*)(xg + (size_t)slot * D_MODEL);
  for (int j = threadIdx.x; j < D_MODEL/8; j += 256) {
    float4 v0 = src[j*2], v1 = src[j*2+1];
    f16x8 h;
    h[0]=(f16)v0.x; h[1]=(f16)v0.y; h[2]=(f16)v0.z; h[3]=(f16)v0.w;
    h[4]=(f16)v1.x; h[5]=(f16)v1.y; h[6]=(f16)v1.z; h[7]=(f16)v1.w;
    dst[j] = h;
  }
}

// ---------------- fused w1+v1 fp32 -> interleaved f16 w12h [E][512 blk16][D] ----------------
__global__ __launch_bounds__(256) void convert_both_kernel(
    const float* __restrict__ w1, const float* __restrict__ v1,
    f16* __restrict__ dst) {
  int n8 = NEXP*FFN*D_MODEL/8;
  int stride = gridDim.x * 256;
  for (int i = blockIdx.x*256 + threadIdx.x; i < n8; i += stride) {
    int d8 = i & (D_MODEL/8 - 1);
    int fr_glob = i >> 8;            // / (D_MODEL/8)
    int e = fr_glob >> 12;           // / FFN
    int fr = fr_glob & (FFN - 1);
    int crbase = ((fr >> 4)*2)*16 + (fr & 15);
    float4 a0 = ((const float4*)w1)[(size_t)i*2];
    float4 a1 = ((const float4*)w1)[(size_t)i*2 + 1];
    float4 b0 = ((const float4*)v1)[(size_t)i*2];
    float4 b1 = ((const float4*)v1)[(size_t)i*2 + 1];
    f16x8 ha, hb;
    ha[0]=(f16)a0.x; ha[1]=(f16)a0.y; ha[2]=(f16)a0.z; ha[3]=(f16)a0.w;
    ha[4]=(f16)a1.x; ha[5]=(f16)a1.y; ha[6]=(f16)a1.z; ha[7]=(f16)a1.w;
    hb[0]=(f16)b0.x; hb[1]=(f16)b0.y; hb[2]=(f16)b0.z; hb[3]=(f16)b0.w;
    hb[4]=(f16)b1.x; hb[5]=(f16)b1.y; hb[6]=(f16)b1.z; hb[7]=(f16)b1.w;
    size_t base = ((size_t)e*FFN2 + crbase)*(D_MODEL/8) + d8;
    ((f16x8*)dst)[base] = ha;
    ((f16x8*)dst)[base + 16*(D_MODEL/8)] = hb;
  }
}

// ---------------- w2 [E][F][D] fp32 -> w2t [E][D][F] f16 ----------------
__global__ __launch_bounds__(256) void transpose_w2_kernel(
    const float* __restrict__ w2, f16* __restrict__ w2t) {
  __shared__ float tl[64][65];
  int e = blockIdx.z;
  int d0 = blockIdx.x * 64, f0 = blockIdx.y * 64;
  const float* src = w2 + (size_t)e * FFN * D_MODEL;
  int tid = threadIdx.x;
  int fr = tid >> 4, c4 = (tid & 15) * 4;
#pragma unroll
  for (int rr = 0; rr < 4; rr++) {
    float4 v = *(const float4*)(src + (size_t)(f0 + fr + rr*16) * D_MODEL + d0 + c4);
    tl[fr + rr*16][c4+0] = v.x; tl[fr + rr*16][c4+1] = v.y;
    tl[fr + rr*16][c4+2] = v.z; tl[fr + rr*16][c4+3] = v.w;
  }
  __syncthreads();
  int dr = tid >> 2, fg = (tid & 3) * 16;
  f16* dst = w2t + (size_t)e * D_MODEL * FFN + (size_t)(d0 + dr) * FFN + f0 + fg;
  f16 tmp[16];
#pragma unroll
  for (int j = 0; j < 16; j++) tmp[j] = (f16)tl[fg + j][dr];
  *(float4*)(dst)     = *(float4*)(tmp);
  *(float4*)(dst + 8) = *(float4*)(tmp + 8);
}

// ---------------- phase A: h = silu(x1)*x2, x1/x2 via interleaved B ----------------
// Natural grid order (x = col panel, y = tile): concurrent blocks sweep
// consecutive tiles; same-expert B-panels stay L3-hot (R6 lesson).
__global__ __launch_bounds__(512, 2) void phaseA_kernel(
    const f16* __restrict__ xg, const f16* __restrict__ w12h,
    f16* __restrict__ hbuf, const int4* __restrict__ sched, const int* __restrict__ nT) {
  int tile = blockIdx.y;
  if (tile >= *nT) return;
  int4 sc = sched[tile];
  int e = sc.x, row0 = sc.y;
  int fc0 = blockIdx.x * BN;                      // combined col base

  __shared__ f16 AS[2][BM*BK];
  __shared__ f16 BS[2][BN*BK];

  int tid = threadIdx.x, lane = tid & 63, wid = tid >> 6;
  int wrM = wid >> 2, wcN = wid & 3;

  const f16* aT = xg  + (size_t)row0 * D_MODEL;
  const f16* bT = w12h + (size_t)e * FFN2 * D_MODEL + (size_t)fc0 * D_MODEL;

  f32x4 acc[8][4];
  f32x4 z4 = {0.f,0.f,0.f,0.f};
#pragma unroll
  for (int m = 0; m < 8; m++)
#pragma unroll
    for (int n = 0; n < 4; n++) acc[m][n] = z4;

  // prologue: full tiles 0 and 1 (16 loads); vmcnt(8) -> tile 0 landed
  stageA<D_MODEL>(aT, 0, AS[0], 0, tid);
  stageA<D_MODEL>(aT, 0, AS[0], 1, tid);
  stageB<D_MODEL>(bT, 0, BS[0], 0, tid);
  stageB<D_MODEL>(bT, 0, BS[0], 1, tid);
  stageA<D_MODEL>(aT, BK, AS[1], 0, tid);
  stageA<D_MODEL>(aT, BK, AS[1], 1, tid);
  stageB<D_MODEL>(bT, BK, BS[1], 0, tid);
  stageB<D_MODEL>(bT, BK, BS[1], 1, tid);
  waitvm<8>();
  __builtin_amdgcn_s_barrier();

  constexpr int NTILES = D_MODEL / BK;            // 32
  for (int t = 0; t + 2 < NTILES; t++) {
    int b = t & 1;
    tile4v2<D_MODEL,8,true>(aT, bT, (t+2)*BK, AS[b], BS[b],
                            acc, tid, lane, wrM, wcN);
  }
  tile4v2<D_MODEL,0,false>(aT, bT, 0, AS[(NTILES-2)&1], BS[(NTILES-2)&1],
                           acc, tid, lane, wrM, wcN);
  tile4v2<D_MODEL,-1,false>(aT, bT, 0, AS[(NTILES-1)&1], BS[(NTILES-1)&1],
                            acc, tid, lane, wrM, wcN);

  // epilogue: pairs (nf even=x1, odd=x2) share (row, f) exactly
  int i15 = lane & 15, l4 = lane >> 4;
#pragma unroll
  for (int m = 0; m < 8; m++) {
    int rowl = wrM*128 + (m>>2)*64 + (m&3)*16 + l4*4;
#pragma unroll
    for (int nh = 0; nh < 2; nh++) {
      int f = (fc0 >> 1) + wcN*32 + nh*16 + i15;
      f16* hb = hbuf + (size_t)(row0 + rowl) * FFN + f;
#pragma unroll
      for (int q2 = 0; q2 < 4; q2++) {
        float x1 = acc[m][nh*2+0][q2], x2 = acc[m][nh*2+1][q2];
        float hv = x1 / (1.0f + __expf(-x1)) * x2;
        hb[(size_t)q2 * FFN] = (f16)hv;
      }
    }
  }
}

// ---------------- phase B: ybuf_z[slot] = h @ w2t^T over K-slice z (no atomics) ----------------
__global__ __launch_bounds__(512, 2) void phaseB_kernel(
    const f16* __restrict__ hbuf, const f16* __restrict__ w2t,
    f16* __restrict__ yb0, f16* __restrict__ ybR,
    const int4* __restrict__ sched, const int* __restrict__ nT) {
  int tile = blockIdx.y;
  if (tile >= *nT) return;
  int4 sc = sched[tile];
  int e = sc.x, row0 = sc.y;
  int dc0 = blockIdx.x * BN;
  int z = blockIdx.z;                              // K-split slice

  __shared__ f16 AS[2][BM*BK];
  __shared__ f16 BS[2][BN*BK];

  int tid = threadIdx.x, lane = tid & 63, wid = tid >> 6;
  int wrM = wid >> 2, wcN = wid & 3;

  const f16* aT = hbuf + (size_t)row0 * FFN + z * KCHUNK;
  const f16* bT = w2t + (size_t)e * D_MODEL * FFN + (size_t)dc0 * FFN + z * KCHUNK;

  f32x4 acc[8][4];
  f32x4 z4 = {0.f,0.f,0.f,0.f};
#pragma unroll
  for (int m = 0; m < 8; m++)
#pragma unroll
    for (int n = 0; n < 4; n++) acc[m][n] = z4;

  stageA<FFN>(aT, 0, AS[0], 0, tid);
  stageA<FFN>(aT, 0, AS[0], 1, tid);
  stageB<FFN>(bT, 0, BS[0], 0, tid);
  stageB<FFN>(bT, 0, BS[0], 1, tid);
  stageA<FFN>(aT, BK, AS[1], 0, tid);
  stageA<FFN>(aT, BK, AS[1], 1, tid);
  stageB<FFN>(bT, BK, BS[1], 0, tid);
  stageB<FFN>(bT, BK, BS[1], 1, tid);
  waitvm<8>();
  __builtin_amdgcn_s_barrier();

  constexpr int NTILES = KCHUNK / BK;              // 16
  for (int t = 0; t + 2 < NTILES; t++) {
    int b = t & 1;
    tile4v2<FFN,8,true>(aT, bT, (t+2)*BK, AS[b], BS[b],
                        acc, tid, lane, wrM, wcN);
  }
  tile4v2<FFN,0,false>(aT, bT, 0, AS[(NTILES-2)&1], BS[(NTILES-2)&1],
                       acc, tid, lane, wrM, wcN);
  tile4v2<FFN,-1,false>(aT, bT, 0, AS[(NTILES-1)&1], BS[(NTILES-1)&1],
                        acc, tid, lane, wrM, wcN);

  // epilogue: plain f16 stores to this slice's ybuf (padded rows harmless)
  f16* yb = (z == 0) ? yb0 : (ybR + (size_t)(z-1) * MAX_ROWS * D_MODEL);
  int i15 = lane & 15, l4 = lane >> 4;
#pragma unroll
  for (int m = 0; m < 8; m++) {
#pragma unroll
    for (int q2 = 0; q2 < 4; q2++) {
      int rl = wrM*128 + (m>>2)*64 + (m&3)*16 + l4*4 + q2;
      f16* yrow = yb + (size_t)(row0 + rl) * D_MODEL + dc0 + wcN*64;
#pragma unroll
      for (int n = 0; n < 4; n++)
        yrow[(n>>1)*32 + (n&1)*16 + i15] = (f16)acc[m][n][q2];
    }
  }
}

// ---------------- combine: out[t] = c0*sum_z yb_z[s0] + c1*sum_z yb_z[s1] ----------------
__global__ __launch_bounds__(256) void combine_kernel(
    const f16* __restrict__ yb0, const f16* __restrict__ ybR,
    const int* __restrict__ te, const float* __restrict__ tw,
    const int* __restrict__ trank, const int* __restrict__ offsets,
    float* __restrict__ out) {
  int t = blockIdx.x;
  int d8 = threadIdx.x;                            // d = d8*8
  int s0 = offsets[te[2*t]]   + trank[2*t];
  int s1 = offsets[te[2*t+1]] + trank[2*t+1];
  float w0 = tw[2*t], w1 = tw[2*t+1];
  float sum[8] = {0.f,0.f,0.f,0.f,0.f,0.f,0.f,0.f};
#pragma unroll
  for (int z = 0; z < KSPLIT; z++) {
    const f16* yb = (z == 0) ? yb0 : (ybR + (size_t)(z-1) * MAX_ROWS * D_MODEL);
    f16x8 a = ((const f16x8*)(yb + (size_t)s0 * D_MODEL))[d8];
    f16x8 b = ((const f16x8*)(yb + (size_t)s1 * D_MODEL))[d8];
#pragma unroll
    for (int j = 0; j < 8; j++) sum[j] += w0 * (float)a[j] + w1 * (float)b[j];
  }
  float* o = out + (size_t)t * D_MODEL + d8*8;
  float4 o0 = {sum[0], sum[1], sum[2], sum[3]};
  float4 o1 = {sum[4], sum[5], sum[6], sum[7]};
  ((float4*)o)[0] = o0;
  ((float4*)o)[1] = o1;
}

// ---------------- host launch ----------------
extern "C" void kernel_launch(void* const* d_in, const int* in_sizes, int n_in,
                              void* d_out, int out_size, void* d_ws, size_t ws_size,
                              hipStream_t stream) {
  const float* x  = (const float*)d_in[0];
  const float* rw = (const float*)d_in[1];
  const float* w1 = (const float*)d_in[2];
  const float* v1 = (const float*)d_in[3];
  const float* w2 = (const float*)d_in[4];
  float* out = (float*)d_out;

  char* p = (char*)d_ws;
  auto alloc = [&](size_t bytes) {
    char* r = p;
    p += (bytes + 255) & ~(size_t)255;
    return r;
  };
  int*   counts   = (int*)  alloc(NEXP * 4);
  int*   nT       = (int*)  alloc(4);
  int*   offsets  = (int*)  alloc((NEXP + 1) * 4);
  int*   te       = (int*)  alloc(NENT * 4);
  float* tw       = (float*)alloc(NENT * 4);
  int*   trank    = (int*)  alloc(NENT * 4);
  int*   token_of = (int*)  alloc(MAX_ROWS * 4);
  float* coefs    = (float*)alloc(MAX_ROWS * 4);
  int4*  sched    = (int4*) alloc(MAX_TILES * 16);
  f16*   xg       = (f16*)  alloc((size_t)MAX_ROWS * D_MODEL * 2);
  f16*   hbuf     = (f16*)  alloc((size_t)MAX_ROWS * FFN * 2);
  f16*   w12h     = (f16*)  alloc((size_t)NEXP * FFN2 * D_MODEL * 2);
  f16*   w2t      = (f16*)  alloc((size_t)NEXP * FFN * D_MODEL * 2);
  size_t needed = (size_t)(p - (char*)d_ws);
  if (needed > ws_size) {
    fprintf(stderr, "kernel_launch: ws too small: need %zu, have %zu\n", needed, ws_size);
    return;
  }
  // ybuf K-split slices alias dead-after-phaseA regions (zero ws growth):
  // slice 0 -> xg (exactly MAX_ROWS*D_MODEL f16); slices 1..3 -> w12h (268MB >= 3*42MB)
  f16* yb0 = xg;
  f16* ybR = w12h;

  zero_counts_kernel<<<1, 64, 0, stream>>>(counts);
  router_kernel<<<NTOK, 64, 0, stream>>>(x, rw, counts, te, tw, trank);
  sched_kernel<<<1, 1, 0, stream>>>(counts, offsets, sched, nT);
  gather_kernel<<<NENT, 256, 0, stream>>>(x, te, tw, trank, offsets, xg, token_of, coefs);
  convert_both_kernel<<<4096, 256, 0, stream>>>(w1, v1, w12h);
  transpose_w2_kernel<<<dim3(D_MODEL/64, FFN/64, NEXP), 256, 0, stream>>>(w2, w2t);
  phaseA_kernel<<<dim3(FFN2/BN, MAX_TILES), 512, 0, stream>>>(xg, w12h, hbuf, sched, nT);
  phaseB_kernel<<<dim3(D_MODEL/BN, MAX_TILES, KSPLIT), 512, 0, stream>>>(hbuf, w2t, yb0, ybR, sched, nT);
  combine_kernel<<<NTOK, 256, 0, stream>>>(yb0, ybR, te, tw, trank, offsets, out);
}

// Round 12
// 892.317 us; speedup vs baseline: 1.1798x; 1.1798x over previous
//
#include <hip/hip_runtime.h>
#include <cstdio>
#include <cstdint>

typedef _Float16 f16;
typedef _Float16 f16x8 __attribute__((ext_vector_type(8)));
typedef float f32x4 __attribute__((ext_vector_type(4)));

#define D_MODEL 2048
#define FFN     4096
#define FFN2    8192
#define NEXP    8
#define NTOK    4096
#define NENT    (NTOK*2)
#define BM      256
#define BN      256
#define BK      64
#define KSPLIT  4
#define KCHUNK  (FFN / KSPLIT)   // 1024
#define MAX_ROWS  10240  // sum over experts of ceil(cnt/256)*256 <= 10232
#define MAX_TILES 40     // sum ceil(cnt/256) <= 39

__device__ __forceinline__ void gload_lds16(const void* g, void* l) {
  __builtin_amdgcn_global_load_lds(
      (const __attribute__((address_space(1))) void*)g,
      (__attribute__((address_space(3))) void*)l, 16, 0, 0);
}

template<int N> __device__ __forceinline__ void waitvm() {
  if constexpr (N == 0) asm volatile("s_waitcnt vmcnt(0)" ::: "memory");
  else if constexpr (N == 2) asm volatile("s_waitcnt vmcnt(2)" ::: "memory");
  // N < 0: no wait
}

// ---- staging: chunk = what one compute phase consumes (16KB, 2 gload_lds/thread).
// LDS storage permutation: A storage row = mh*128 + wrM*64 + (r&63)
//                          B storage row = nh*128 + g*32 + i  (col c = g*64+nh*32+i)
// plus byte-XOR swizzle ((srow&7)<<4) folded into the per-lane GLOBAL source
// address (dest stays linear for global_load_lds; rule #21).
template<int LD>
__device__ __forceinline__ void stageA(const f16* aT, int k0, f16* AS, int mh, int tid) {
#pragma unroll
  for (int s = 0; s < 2; s++) {
    int o = s*8192 + tid*16;
    int rl = o >> 7;                                  // storage-local row 0..127
    int ce = ((o & 127) ^ ((rl & 7) << 4)) >> 1;      // pre-swizzled source col (f16)
    int arow = s*128 + mh*64 + (rl & 63);             // actual A row in tile
    gload_lds16(aT + (size_t)arow * LD + k0 + ce,
                (char*)AS + mh*16384 + s*8192 + (tid & ~63)*16);
  }
}

template<int LD>
__device__ __forceinline__ void stageB(const f16* bT, int k0, f16* BS, int nh, int tid) {
#pragma unroll
  for (int s = 0; s < 2; s++) {
    int o = s*8192 + tid*16;
    int rl = o >> 7;
    int ce = ((o & 127) ^ ((rl & 7) << 4)) >> 1;
    int crow = (rl >> 5)*64 + nh*32 + (rl & 31);      // actual B row (tile col)
    gload_lds16(bT + (size_t)crow * LD + k0 + ce,
                (char*)BS + nh*16384 + s*8192 + (tid & ~63)*16);
  }
}

__device__ __forceinline__ f16x8 fragLd(const f16* S, int row, int lane, int ks) {
  int kb = ks*64 + (lane >> 4)*16;
  int off = (row*128 + kb) ^ ((row & 7) << 4);
  return *(const f16x8*)((const char*)S + off);
}

// ---- one K-tile = 4 phases (one output quadrant each).
// R10 ledger: NO mid-tile vmcnt; ONE tile-end vmcnt(2). Induction: entering
// tile t, exactly A-half0(t+1)'s 2 loads in flight; issues during t: ph0
// B0(t+1), ph1 B1(t+1), ph2 A1(t+1), ph3 A0(t+2). End vmcnt(2) retires the
// 8 oldest = everything tile t+1 reads. Tails: NT-2 -> vmcnt(0), NT-1 -> none.
// [Anchor structure: phaseA 346us/41% MfmaUtil. Schedule-lane ledger: this >
//  persistent(420) ~ hoisted-2ph(423) > reads-early-regs(446, spill) >
//  reg-fused-B(761, spill). Fragments must be loaded just-in-time per phase:
//  at acc=128 AGPR + 2 waves/SIMD the arch-VGPR cap is 128 - any schedule
//  holding a full tile of fragments spills (R9/R11). DO NOT TOUCH.]
template<int LD, int V0, int V1, int V3, bool SB0, bool SB1, bool SA1, bool SA0>
__device__ __forceinline__ void tile4(
    const f16* aT, const f16* bT, int k1, int k2,
    f16* ASc, f16* BSc, f16* ASn, f16* BSn,
    f32x4 (&acc)[8][4], f16x8 (&aF)[4][2], f16x8 (&bF)[2][2][2],
    int tid, int lane, int wrM, int wcN) {
  // ---- phase 0: quadrant (0,0) — read A-half0 + B-half0
#pragma unroll
  for (int mf = 0; mf < 4; mf++)
#pragma unroll
    for (int ks = 0; ks < 2; ks++)
      aF[mf][ks] = fragLd(ASc, wrM*64 + mf*16 + (lane & 15), lane, ks);
#pragma unroll
  for (int nf = 0; nf < 2; nf++)
#pragma unroll
    for (int ks = 0; ks < 2; ks++)
      bF[0][nf][ks] = fragLd(BSc, wcN*32 + nf*16 + (lane & 15), lane, ks);
  if constexpr (SB0) stageB<LD>(bT, k1, BSn, 0, tid);
  __builtin_amdgcn_s_barrier();
  __builtin_amdgcn_s_setprio(1);
#pragma unroll
  for (int mf = 0; mf < 4; mf++)
#pragma unroll
    for (int nf = 0; nf < 2; nf++)
#pragma unroll
      for (int ks = 0; ks < 2; ks++)
        acc[mf][nf] = __builtin_amdgcn_mfma_f32_16x16x32_f16(aF[mf][ks], bF[0][nf][ks], acc[mf][nf], 0, 0, 0);
  __builtin_amdgcn_s_setprio(0);
  waitvm<V0>();
  __builtin_amdgcn_s_barrier();
  // ---- phase 1: quadrant (0,1) — read B-half1
#pragma unroll
  for (int nf = 0; nf < 2; nf++)
#pragma unroll
    for (int ks = 0; ks < 2; ks++)
      bF[1][nf][ks] = fragLd(BSc, 128 + wcN*32 + nf*16 + (lane & 15), lane, ks);
  if constexpr (SB1) stageB<LD>(bT, k1, BSn, 1, tid);
  __builtin_amdgcn_s_barrier();
  __builtin_amdgcn_s_setprio(1);
#pragma unroll
  for (int mf = 0; mf < 4; mf++)
#pragma unroll
    for (int nf = 0; nf < 2; nf++)
#pragma unroll
      for (int ks = 0; ks < 2; ks++)
        acc[mf][2+nf] = __builtin_amdgcn_mfma_f32_16x16x32_f16(aF[mf][ks], bF[1][nf][ks], acc[mf][2+nf], 0, 0, 0);
  __builtin_amdgcn_s_setprio(0);
  waitvm<V1>();
  __builtin_amdgcn_s_barrier();
  // ---- phase 2: quadrant (1,0) — read A-half1 (overwrite aF)
#pragma unroll
  for (int mf = 0; mf < 4; mf++)
#pragma unroll
    for (int ks = 0; ks < 2; ks++)
      aF[mf][ks] = fragLd(ASc, 128 + wrM*64 + mf*16 + (lane & 15), lane, ks);
  if constexpr (SA1) stageA<LD>(aT, k1, ASn, 1, tid);
  __builtin_amdgcn_s_barrier();
  __builtin_amdgcn_s_setprio(1);
#pragma unroll
  for (int mf = 0; mf < 4; mf++)
#pragma unroll
    for (int nf = 0; nf < 2; nf++)
#pragma unroll
      for (int ks = 0; ks < 2; ks++)
        acc[4+mf][nf] = __builtin_amdgcn_mfma_f32_16x16x32_f16(aF[mf][ks], bF[0][nf][ks], acc[4+mf][nf], 0, 0, 0);
  __builtin_amdgcn_s_setprio(0);
  __builtin_amdgcn_s_barrier();
  // ---- phase 3: quadrant (1,1) — no reads; stage A-half0(t+2) into CURRENT buf
  if constexpr (SA0) stageA<LD>(aT, k2, ASc, 0, tid);
  __builtin_amdgcn_s_barrier();
  __builtin_amdgcn_s_setprio(1);
#pragma unroll
  for (int mf = 0; mf < 4; mf++)
#pragma unroll
    for (int nf = 0; nf < 2; nf++)
#pragma unroll
      for (int ks = 0; ks < 2; ks++)
        acc[4+mf][2+nf] = __builtin_amdgcn_mfma_f32_16x16x32_f16(aF[mf][ks], bF[1][nf][ks], acc[4+mf][2+nf], 0, 0, 0);
  __builtin_amdgcn_s_setprio(0);
  waitvm<V3>();
  __builtin_amdgcn_s_barrier();
}

// ---------------- utility kernels ----------------

__global__ void zero_counts_kernel(int* counts) {
  if (threadIdx.x < NEXP) counts[threadIdx.x] = 0;
}

// ---------------- router ----------------
__global__ __launch_bounds__(64) void router_kernel(
    const float* __restrict__ x, const float* __restrict__ rw,
    int* counts, int* te, float* tw, int* trank) {
  int t = blockIdx.x;
  int lane = threadIdx.x;
  float acc[8] = {0.f,0.f,0.f,0.f,0.f,0.f,0.f,0.f};
  const float* xr = x + (size_t)t * D_MODEL;
  for (int d = lane; d < D_MODEL; d += 64) {
    float xv = xr[d];
    const float4* r4 = (const float4*)(rw + (size_t)d * NEXP);
    float4 a = r4[0], b = r4[1];
    acc[0] += xv*a.x; acc[1] += xv*a.y; acc[2] += xv*a.z; acc[3] += xv*a.w;
    acc[4] += xv*b.x; acc[5] += xv*b.y; acc[6] += xv*b.z; acc[7] += xv*b.w;
  }
#pragma unroll
  for (int off = 32; off > 0; off >>= 1) {
#pragma unroll
    for (int e = 0; e < 8; e++) acc[e] += __shfl_down(acc[e], off);
  }
  if (lane == 0) {
    int e0 = 0;
#pragma unroll
    for (int e = 1; e < 8; e++) if (acc[e] > acc[e0]) e0 = e;
    int e1 = (e0 == 0) ? 1 : 0;
#pragma unroll
    for (int e = 0; e < 8; e++) if (e != e0 && acc[e] > acc[e1]) e1 = e;
    float c0 = 1.0f / (1.0f + expf(acc[e1] - acc[e0]));   // == softmax-top2 L1-renorm
    float c1 = 1.0f - c0;
    int r0 = atomicAdd(&counts[e0], 1);
    int r1 = atomicAdd(&counts[e1], 1);
    te[t*2] = e0; te[t*2+1] = e1;
    tw[t*2] = c0; tw[t*2+1] = c1;
    trank[t*2] = r0; trank[t*2+1] = r1;
  }
}

// ---------------- scan + tile schedule ----------------
__global__ void sched_kernel(const int* counts, int* offsets, int4* sched, int* nT) {
  if (threadIdx.x != 0 || blockIdx.x != 0) return;
  int off = 0, n = 0;
  for (int e = 0; e < NEXP; e++) {
    offsets[e] = off;
    int cnt = counts[e];
    int nt = (cnt + BM - 1) / BM;
    for (int i = 0; i < nt; i++) {
      sched[n] = make_int4(e, off + i*BM, min(BM, cnt - i*BM), 0);
      n++;
    }
    off += nt * BM;
  }
  offsets[NEXP] = off;
  *nT = n;
}

// ---------------- gather x rows -> f16 xg[slot] ----------------
__global__ __launch_bounds__(256) void gather_kernel(
    const float* __restrict__ x, const int* __restrict__ te,
    const float* __restrict__ tw, const int* __restrict__ trank,
    const int* __restrict__ offsets, f16* __restrict__ xg,
    int* __restrict__ token_of, float* __restrict__ coefs) {
  int i = blockIdx.x;
  int t = i >> 1;
  int e = te[i];
  int slot = offsets[e] + trank[i];
  if (threadIdx.x == 0) { token_of[slot] = t; coefs[slot] = tw[i]; }
  const float4* src = (const float4*)(x + (size_t)t * D_MODEL);
  f16x8* dst = (f16x8*)(xg + (size_t)slot * D_MODEL);
  for (int j = threadIdx.x; j < D_MODEL/8; j += 256) {
    float4 v0 = src[j*2], v1 = src[j*2+1];
    f16x8 h;
    h[0]=(f16)v0.x; h[1]=(f16)v0.y; h[2]=(f16)v0.z; h[3]=(f16)v0.w;
    h[4]=(f16)v1.x; h[5]=(f16)v1.y; h[6]=(f16)v1.z; h[7]=(f16)v1.w;
    dst[j] = h;
  }
}

// ---------------- fused w1+v1 fp32 -> interleaved f16 w12h [E][512 blk16][D] ----------------
// combined row cr = ((fr>>4)*2 + parity)*16 + (fr&15): even 16-blocks from w1, odd from v1
__global__ __launch_bounds__(256) void convert_both_kernel(
    const float* __restrict__ w1, const float* __restrict__ v1,
    f16* __restrict__ dst) {
  int n8 = NEXP*FFN*D_MODEL/8;
  int stride = gridDim.x * 256;
  for (int i = blockIdx.x*256 + threadIdx.x; i < n8; i += stride) {
    int d8 = i & (D_MODEL/8 - 1);
    int fr_glob = i >> 8;            // / (D_MODEL/8)
    int e = fr_glob >> 12;           // / FFN
    int fr = fr_glob & (FFN - 1);
    int crbase = ((fr >> 4)*2)*16 + (fr & 15);
    float4 a0 = ((const float4*)w1)[(size_t)i*2];
    float4 a1 = ((const float4*)w1)[(size_t)i*2 + 1];
    float4 b0 = ((const float4*)v1)[(size_t)i*2];
    float4 b1 = ((const float4*)v1)[(size_t)i*2 + 1];
    f16x8 ha, hb;
    ha[0]=(f16)a0.x; ha[1]=(f16)a0.y; ha[2]=(f16)a0.z; ha[3]=(f16)a0.w;
    ha[4]=(f16)a1.x; ha[5]=(f16)a1.y; ha[6]=(f16)a1.z; ha[7]=(f16)a1.w;
    hb[0]=(f16)b0.x; hb[1]=(f16)b0.y; hb[2]=(f16)b0.z; hb[3]=(f16)b0.w;
    hb[4]=(f16)b1.x; hb[5]=(f16)b1.y; hb[6]=(f16)b1.z; hb[7]=(f16)b1.w;
    size_t base = ((size_t)e*FFN2 + crbase)*(D_MODEL/8) + d8;
    ((f16x8*)dst)[base] = ha;
    ((f16x8*)dst)[base + 16*(D_MODEL/8)] = hb;
  }
}

// ---------------- w2 [E][F][D] fp32 -> w2t [E][D][F] f16 ----------------
__global__ __launch_bounds__(256) void transpose_w2_kernel(
    const float* __restrict__ w2, f16* __restrict__ w2t) {
  __shared__ float tl[64][65];
  int e = blockIdx.z;
  int d0 = blockIdx.x * 64, f0 = blockIdx.y * 64;
  const float* src = w2 + (size_t)e * FFN * D_MODEL;
  int tid = threadIdx.x;
  int fr = tid >> 4, c4 = (tid & 15) * 4;
#pragma unroll
  for (int rr = 0; rr < 4; rr++) {
    float4 v = *(const float4*)(src + (size_t)(f0 + fr + rr*16) * D_MODEL + d0 + c4);
    tl[fr + rr*16][c4+0] = v.x; tl[fr + rr*16][c4+1] = v.y;
    tl[fr + rr*16][c4+2] = v.z; tl[fr + rr*16][c4+3] = v.w;
  }
  __syncthreads();
  int dr = tid >> 2, fg = (tid & 3) * 16;
  f16* dst = w2t + (size_t)e * D_MODEL * FFN + (size_t)(d0 + dr) * FFN + f0 + fg;
  f16 tmp[16];
#pragma unroll
  for (int j = 0; j < 16; j++) tmp[j] = (f16)tl[fg + j][dr];
  *(float4*)(dst)     = *(float4*)(tmp);
  *(float4*)(dst + 8) = *(float4*)(tmp + 8);
}

// ---------------- phase A: h = silu(x1)*x2, x1/x2 via interleaved B ----------------
// Natural grid order (x = col panel, y = tile): concurrent blocks sweep
// consecutive tiles; same-expert B-panels stay L3-hot (R6 lesson).
__global__ __launch_bounds__(512, 2) void phaseA_kernel(
    const f16* __restrict__ xg, const f16* __restrict__ w12h,
    f16* __restrict__ hbuf, const int4* __restrict__ sched, const int* __restrict__ nT) {
  int tile = blockIdx.y;
  if (tile >= *nT) return;
  int4 sc = sched[tile];
  int e = sc.x, row0 = sc.y;
  int fc0 = blockIdx.x * BN;                      // combined col base

  __shared__ f16 AS[2][BM*BK];
  __shared__ f16 BS[2][BN*BK];

  int tid = threadIdx.x, lane = tid & 63, wid = tid >> 6;
  int wrM = wid >> 2, wcN = wid & 3;

  const f16* aT = xg  + (size_t)row0 * D_MODEL;
  const f16* bT = w12h + (size_t)e * FFN2 * D_MODEL + (size_t)fc0 * D_MODEL;

  f32x4 acc[8][4]; f16x8 aF[4][2]; f16x8 bF[2][2][2];
  f32x4 z4 = {0.f,0.f,0.f,0.f};
#pragma unroll
  for (int m = 0; m < 8; m++)
#pragma unroll
    for (int n = 0; n < 4; n++) acc[m][n] = z4;

  // prologue: A0(0), B0(0), B1(0), A1(0), A0(1); vmcnt(2) leaves A0(1) in flight
  stageA<D_MODEL>(aT, 0, AS[0], 0, tid);
  stageB<D_MODEL>(bT, 0, BS[0], 0, tid);
  stageB<D_MODEL>(bT, 0, BS[0], 1, tid);
  stageA<D_MODEL>(aT, 0, AS[0], 1, tid);
  stageA<D_MODEL>(aT, BK, AS[1], 0, tid);
  waitvm<2>();
  __builtin_amdgcn_s_barrier();

  constexpr int NTILES = D_MODEL / BK;            // 32
  for (int t = 0; t + 2 < NTILES; t++) {
    int b = t & 1;
    tile4<D_MODEL,-1,-1,2,true,true,true,true>(aT, bT, (t+1)*BK, (t+2)*BK,
        AS[b], BS[b], AS[b^1], BS[b^1], acc, aF, bF, tid, lane, wrM, wcN);
  }
  { int b = (NTILES-2) & 1;
    tile4<D_MODEL,-1,-1,0,true,true,true,false>(aT, bT, (NTILES-1)*BK, 0,
        AS[b], BS[b], AS[b^1], BS[b^1], acc, aF, bF, tid, lane, wrM, wcN); }
  { int b = (NTILES-1) & 1;
    tile4<D_MODEL,-1,-1,-1,false,false,false,false>(aT, bT, 0, 0,
        AS[b], BS[b], AS[b^1], BS[b^1], acc, aF, bF, tid, lane, wrM, wcN); }

  // epilogue: pairs (nf even=x1, odd=x2) share (row, f) exactly
  int i15 = lane & 15, l4 = lane >> 4;
#pragma unroll
  for (int m = 0; m < 8; m++) {
    int rowl = wrM*128 + (m>>2)*64 + (m&3)*16 + l4*4;
#pragma unroll
    for (int nh = 0; nh < 2; nh++) {
      int f = (fc0 >> 1) + wcN*32 + nh*16 + i15;
      f16* hb = hbuf + (size_t)(row0 + rowl) * FFN + f;
#pragma unroll
      for (int q2 = 0; q2 < 4; q2++) {
        float x1 = acc[m][nh*2+0][q2], x2 = acc[m][nh*2+1][q2];
        float hv = x1 / (1.0f + __expf(-x1)) * x2;
        hb[(size_t)q2 * FFN] = (f16)hv;
      }
    }
  }
}

// ---------------- phase B: ybuf_z[slot] = h @ w2t^T over K-slice z (no atomics) ----------------
__global__ __launch_bounds__(512, 2) void phaseB_kernel(
    const f16* __restrict__ hbuf, const f16* __restrict__ w2t,
    f16* __restrict__ yb0, f16* __restrict__ ybR,
    const int4* __restrict__ sched, const int* __restrict__ nT) {
  int tile = blockIdx.y;
  if (tile >= *nT) return;
  int4 sc = sched[tile];
  int e = sc.x, row0 = sc.y;
  int dc0 = blockIdx.x * BN;
  int z = blockIdx.z;                              // K-split slice

  __shared__ f16 AS[2][BM*BK];
  __shared__ f16 BS[2][BN*BK];

  int tid = threadIdx.x, lane = tid & 63, wid = tid >> 6;
  int wrM = wid >> 2, wcN = wid & 3;

  const f16* aT = hbuf + (size_t)row0 * FFN + z * KCHUNK;
  const f16* bT = w2t + (size_t)e * D_MODEL * FFN + (size_t)dc0 * FFN + z * KCHUNK;

  f32x4 acc[8][4]; f16x8 aF[4][2]; f16x8 bF[2][2][2];
  f32x4 z4 = {0.f,0.f,0.f,0.f};
#pragma unroll
  for (int m = 0; m < 8; m++)
#pragma unroll
    for (int n = 0; n < 4; n++) acc[m][n] = z4;

  stageA<FFN>(aT, 0, AS[0], 0, tid);
  stageB<FFN>(bT, 0, BS[0], 0, tid);
  stageB<FFN>(bT, 0, BS[0], 1, tid);
  stageA<FFN>(aT, 0, AS[0], 1, tid);
  stageA<FFN>(aT, BK, AS[1], 0, tid);
  waitvm<2>();
  __builtin_amdgcn_s_barrier();

  constexpr int NTILES = KCHUNK / BK;              // 16
  for (int t = 0; t + 2 < NTILES; t++) {
    int b = t & 1;
    tile4<FFN,-1,-1,2,true,true,true,true>(aT, bT, (t+1)*BK, (t+2)*BK,
        AS[b], BS[b], AS[b^1], BS[b^1], acc, aF, bF, tid, lane, wrM, wcN);
  }
  { int b = (NTILES-2) & 1;
    tile4<FFN,-1,-1,0,true,true,true,false>(aT, bT, (NTILES-1)*BK, 0,
        AS[b], BS[b], AS[b^1], BS[b^1], acc, aF, bF, tid, lane, wrM, wcN); }
  { int b = (NTILES-1) & 1;
    tile4<FFN,-1,-1,-1,false,false,false,false>(aT, bT, 0, 0,
        AS[b], BS[b], AS[b^1], BS[b^1], acc, aF, bF, tid, lane, wrM, wcN); }

  // epilogue: plain f16 stores to this slice's ybuf (padded rows harmless)
  f16* yb = (z == 0) ? yb0 : (ybR + (size_t)(z-1) * MAX_ROWS * D_MODEL);
  int i15 = lane & 15, l4 = lane >> 4;
#pragma unroll
  for (int m = 0; m < 8; m++) {
#pragma unroll
    for (int q2 = 0; q2 < 4; q2++) {
      int rl = wrM*128 + (m>>2)*64 + (m&3)*16 + l4*4 + q2;
      f16* yrow = yb + (size_t)(row0 + rl) * D_MODEL + dc0 + wcN*64;
#pragma unroll
      for (int n = 0; n < 4; n++)
        yrow[(n>>1)*32 + (n&1)*16 + i15] = (f16)acc[m][n][q2];
    }
  }
}

// ---------------- combine: out[t] = c0*sum_z yb_z[s0] + c1*sum_z yb_z[s1] ----------------
__global__ __launch_bounds__(256) void combine_kernel(
    const f16* __restrict__ yb0, const f16* __restrict__ ybR,
    const int* __restrict__ te, const float* __restrict__ tw,
    const int* __restrict__ trank, const int* __restrict__ offsets,
    float* __restrict__ out) {
  int t = blockIdx.x;
  int d8 = threadIdx.x;                            // d = d8*8
  int s0 = offsets[te[2*t]]   + trank[2*t];
  int s1 = offsets[te[2*t+1]] + trank[2*t+1];
  float w0 = tw[2*t], w1 = tw[2*t+1];
  float sum[8] = {0.f,0.f,0.f,0.f,0.f,0.f,0.f,0.f};
#pragma unroll
  for (int z = 0; z < KSPLIT; z++) {
    const f16* yb = (z == 0) ? yb0 : (ybR + (size_t)(z-1) * MAX_ROWS * D_MODEL);
    f16x8 a = ((const f16x8*)(yb + (size_t)s0 * D_MODEL))[d8];
    f16x8 b = ((const f16x8*)(yb + (size_t)s1 * D_MODEL))[d8];
#pragma unroll
    for (int j = 0; j < 8; j++) sum[j] += w0 * (float)a[j] + w1 * (float)b[j];
  }
  float* o = out + (size_t)t * D_MODEL + d8*8;
  float4 o0 = {sum[0], sum[1], sum[2], sum[3]};
  float4 o1 = {sum[4], sum[5], sum[6], sum[7]};
  ((float4*)o)[0] = o0;
  ((float4*)o)[1] = o1;
}

// ---------------- host launch ----------------
extern "C" void kernel_launch(void* const* d_in, const int* in_sizes, int n_in,
                              void* d_out, int out_size, void* d_ws, size_t ws_size,
                              hipStream_t stream) {
  const float* x  = (const float*)d_in[0];
  const float* rw = (const float*)d_in[1];
  const float* w1 = (const float*)d_in[2];
  const float* v1 = (const float*)d_in[3];
  const float* w2 = (const float*)d_in[4];
  float* out = (float*)d_out;

  char* p = (char*)d_ws;
  auto alloc = [&](size_t bytes) {
    char* r = p;
    p += (bytes + 255) & ~(size_t)255;
    return r;
  };
  int*   counts   = (int*)  alloc(NEXP * 4);
  int*   nT       = (int*)  alloc(4);
  int*   offsets  = (int*)  alloc((NEXP + 1) * 4);
  int*   te       = (int*)  alloc(NENT * 4);
  float* tw       = (float*)alloc(NENT * 4);
  int*   trank    = (int*)  alloc(NENT * 4);
  int*   token_of = (int*)  alloc(MAX_ROWS * 4);
  float* coefs    = (float*)alloc(MAX_ROWS * 4);
  int4*  sched    = (int4*) alloc(MAX_TILES * 16);
  f16*   xg       = (f16*)  alloc((size_t)MAX_ROWS * D_MODEL * 2);
  f16*   hbuf     = (f16*)  alloc((size_t)MAX_ROWS * FFN * 2);
  f16*   w12h     = (f16*)  alloc((size_t)NEXP * FFN2 * D_MODEL * 2);
  f16*   w2t      = (f16*)  alloc((size_t)NEXP * FFN * D_MODEL * 2);
  size_t needed = (size_t)(p - (char*)d_ws);
  if (needed > ws_size) {
    fprintf(stderr, "kernel_launch: ws too small: need %zu, have %zu\n", needed, ws_size);
    return;
  }
  // ybuf K-split slices alias dead-after-phaseA regions (zero ws growth):
  // slice 0 -> xg (exactly MAX_ROWS*D_MODEL f16); slices 1..3 -> w12h (268MB >= 3*42MB)
  f16* yb0 = xg;
  f16* ybR = w12h;

  zero_counts_kernel<<<1, 64, 0, stream>>>(counts);
  router_kernel<<<NTOK, 64, 0, stream>>>(x, rw, counts, te, tw, trank);
  sched_kernel<<<1, 1, 0, stream>>>(counts, offsets, sched, nT);
  gather_kernel<<<NENT, 256, 0, stream>>>(x, te, tw, trank, offsets, xg, token_of, coefs);
  convert_both_kernel<<<4096, 256, 0, stream>>>(w1, v1, w12h);
  transpose_w2_kernel<<<dim3(D_MODEL/64, FFN/64, NEXP), 256, 0, stream>>>(w2, w2t);
  phaseA_kernel<<<dim3(FFN2/BN, MAX_TILES), 512, 0, stream>>>(xg, w12h, hbuf, sched, nT);
  phaseB_kernel<<<dim3(D_MODEL/BN, MAX_TILES, KSPLIT), 512, 0, stream>>>(hbuf, w2t, yb0, ybR, sched, nT);
  combine_kernel<<<NTOK, 256, 0, stream>>>(yb0, ybR, te, tw, trank, offsets, out);
}